// Round 4
// baseline (158.216 us; speedup 1.0000x reference)
//
#include <hip/hip_runtime.h>
#include <hip/hip_bf16.h>

#define N_ATOMS 400000
#define BATCHES 64
#define DH 128

// Workspace float layout
#define ACC_OFF 0          // B*17 : [cnt, zsum[12], zsq[4]] per batch
#define UID_OFF 2048       // uid8 bytes start at float offset 2048

typedef float f4 __attribute__((ext_vector_type(4)));

__device__ __forceinline__ f4 ntload4(const f4* p) { return __builtin_nontemporal_load(p); }
__device__ __forceinline__ void ntstore4(f4* p, f4 v) { __builtin_nontemporal_store(v, p); }
__device__ __forceinline__ float silu_f(float x) { return x / (1.f + expf(-x)); }

// ---------------- Kernel 1: per-batch stats (cnt, Zsum, Zsqsum) + uid8 ----------------
__global__ __launch_bounds__(256) void k1_stats(
    const float* __restrict__ Z, const int* __restrict__ block_id,
    const int* __restrict__ batch_id, float* __restrict__ acc,
    unsigned char* __restrict__ uid8) {
  __shared__ float bins[BATCHES * 17];
  for (int i = threadIdx.x; i < BATCHES * 17; i += 256) bins[i] = 0.f;
  __syncthreads();

  const f4* Z4 = (const f4*)Z;
  int n = blockIdx.x * 256 + threadIdx.x;
  bool valid = (n < N_ATOMS);
  int uid = -1;
  float z[12];
#pragma unroll
  for (int j = 0; j < 12; ++j) z[j] = 0.f;
  if (valid) {
    uid = batch_id[block_id[n]];
    uid8[n] = (unsigned char)uid;
    f4 a = Z4[n * 3 + 0];
    f4 b = Z4[n * 3 + 1];
    f4 c = Z4[n * 3 + 2];
    z[0] = a.x; z[1] = a.y; z[2]  = a.z; z[3]  = a.w;
    z[4] = b.x; z[5] = b.y; z[6]  = b.z; z[7]  = b.w;
    z[8] = c.x; z[9] = c.y; z[10] = c.z; z[11] = c.w;
  }

  int lo = valid ? uid : 0x7fffffff;
  int hi = uid;
#pragma unroll
  for (int m = 32; m; m >>= 1) {
    lo = min(lo, __shfl_xor(lo, m));
    hi = max(hi, __shfl_xor(hi, m));
  }

  if (lo == hi) {
    // wave-uniform uid (common case: sorted input)
    float vals[16];
#pragma unroll
    for (int j = 0; j < 12; ++j) vals[j] = z[j];
#pragma unroll
    for (int c = 0; c < 4; ++c)
      vals[12 + c] = z[c*3]*z[c*3] + z[c*3+1]*z[c*3+1] + z[c*3+2]*z[c*3+2];
#pragma unroll
    for (int v = 0; v < 16; ++v) {
      float x = vals[v];
#pragma unroll
      for (int m = 32; m; m >>= 1) x += __shfl_xor(x, m);
      vals[v] = x;
    }
    unsigned long long mb = __ballot(valid);
    if ((threadIdx.x & 63) == 0) {
      atomicAdd(&bins[hi * 17 + 0], (float)__popcll(mb));
#pragma unroll
      for (int v = 0; v < 16; ++v) atomicAdd(&bins[hi * 17 + 1 + v], vals[v]);
    }
  } else if (hi >= 0) {
    // rare: wave straddles a batch boundary -> per-lane LDS atomics
    if (valid) {
      atomicAdd(&bins[uid * 17 + 0], 1.f);
#pragma unroll
      for (int j = 0; j < 12; ++j) atomicAdd(&bins[uid * 17 + 1 + j], z[j]);
#pragma unroll
      for (int c = 0; c < 4; ++c)
        atomicAdd(&bins[uid * 17 + 13 + c],
                  z[c*3]*z[c*3] + z[c*3+1]*z[c*3+1] + z[c*3+2]*z[c*3+2]);
    }
  }
  __syncthreads();
  for (int i = threadIdx.x; i < BATCHES * 17; i += 256) {
    float v = bins[i];
    if (v != 0.f) atomicAdd(&acc[i], v);
  }
}

// ---------------- Kernel 3 (fused MLP + apply) ----------------
// 256 threads, 32 atoms/block. Sorted atoms -> block spans at most 2 batches.
// Block computes the per-batch MLP for its <=2 uid "slots" in LDS while the
// H non-temporal loads are in flight, then applies LN + Z rescale.
__global__ __launch_bounds__(256) void k3_apply(
    const float* __restrict__ H, const float* __restrict__ Z,
    const unsigned char* __restrict__ uid8,
    const float* __restrict__ sigma,
    const float* __restrict__ W1, const float* __restrict__ b1,
    const float* __restrict__ W2, const float* __restrict__ b2,
    const float* __restrict__ ln_w, const float* __restrict__ ln_b,
    const float* __restrict__ acc,
    float* __restrict__ Hout, float* __restrict__ Zout,
    float* __restrict__ resc_out) {
  int t = threadIdx.x;
  int base = blockIdx.x * 32;
  int sub = t >> 4, l = t & 15;
  int n0 = base + sub * 2;
  int n1 = n0 + 1;

  __shared__ float resc_s[2][4];
  __shared__ float zc_s[2][12];
  __shared__ float rbf_s[2][64];
  __shared__ float h1_s[2][128];
  __shared__ float h_s[2][128];
  __shared__ int uidlo_s;

  // per-atom uids (n0 even -> aligned ushort)
  unsigned short u2 = *(const unsigned short*)&uid8[n0];
  int uid0 = u2 & 0xff, uid1 = u2 >> 8;
  if (t == 0) uidlo_s = uid0;  // uid of atom `base`

  // issue streaming loads early; waits land after the MLP phases
  const f4* H4 = (const f4*)H;
  size_t r0 = (size_t)n0 * 32, r1 = (size_t)n1 * 32;
  f4 v00 = ntload4(&H4[r0 + l]);
  f4 v01 = ntload4(&H4[r0 + 16 + l]);
  f4 v10 = ntload4(&H4[r1 + l]);
  f4 v11 = ntload4(&H4[r1 + 16 + l]);

  f4 zv = {0.f, 0.f, 0.f, 0.f};
  int za = 0, zcomp = 0, zuid = 0;
  if (t < 96) {
    za = t / 3;
    zcomp = t - za * 3;
    zuid = uid8[base + za];
    zv = ((const f4*)Z)[(base + za) * 3 + zcomp];
  }

  // --- MLP phase A: rescale (t<8) and centroids (t in [32,56)) ---
  if (t < 8) {
    int slot = t >> 2, c = t & 3;
    int u = uid8[base + (slot ? 31 : 0)];
    float cnt = acc[u * 17];
    float cs = fmaxf(cnt, 1.f);
    float s2 = 0.f;
#pragma unroll
    for (int a = 0; a < 3; ++a) {
      float zc = acc[u * 17 + 1 + c * 3 + a] / cs;
      s2 += zc * zc;
    }
    float sq = acc[u * 17 + 13 + c] - cnt * s2;
    float denom = fmaxf(cnt * 3.f - 1.f, 1.f);
    float var = fmaxf(sq / denom, 0.f);
    float r = sigma[c] / sqrtf(var);
    resc_s[slot][c] = r;
    resc_out[u * 4 + c] = r;  // redundant identical writes across blocks: benign
  }
  if (t >= 32 && t < 56) {
    int tt = t - 32;
    int slot = tt / 12, j = tt - slot * 12;
    int u = uid8[base + (slot ? 31 : 0)];
    float cs = fmaxf(acc[u * 17], 1.f);
    zc_s[slot][j] = acc[u * 17 + 1 + j] / cs;
  }
  __syncthreads();

  // --- MLP phase B: RBF (t<128: slot, 64 basis values) ---
  if (t < 128) {
    int slot = t >> 6, i = t & 63;
    int c = i >> 4, ri = i & 15;
    float ds = resc_s[slot][c] * (1.f / 7.f);
    float env = 0.f;
    if (ds < 1.f) {
      float d2 = ds * ds;
      float d5 = d2 * d2 * ds;
      env = 1.f - 21.f * d5 + 35.f * d5 * ds - 15.f * d5 * d2;
    }
    float off = (float)ri * (1.f / 15.f);
    float dd = ds - off;
    rbf_s[slot][i] = env * expf(-112.5f * dd * dd);
  }
  __syncthreads();

  // --- MLP phase C: h1 = silu(rbf @ W1 + b1), 2 slots x 128 cols ---
  {
    int slot = t >> 7, col = t & 127;
    float s = b1[col];
#pragma unroll 8
    for (int k = 0; k < 64; ++k) s += rbf_s[slot][k] * W1[k * 128 + col];
    h1_s[slot][col] = silu_f(s);
  }
  __syncthreads();

  // --- MLP phase D: h = silu(h1 @ W2 + b2) ---
  {
    int slot = t >> 7, col = t & 127;
    float s = b2[col];
#pragma unroll 8
    for (int k = 0; k < 128; ++k) s += h1_s[slot][k] * W2[k * 128 + col];
    h_s[slot][col] = silu_f(s);
  }
  __syncthreads();

  // --- apply: LN(H + h[uid]) ---
  int uid_lo = uidlo_s;
  int s0 = min(uid0 - uid_lo, 1);
  int s1 = min(uid1 - uid_lo, 1);
  const f4* hs0 = (const f4*)h_s[s0];
  const f4* hs1 = (const f4*)h_s[s1];
  f4 x00 = v00 + hs0[l];
  f4 x01 = v01 + hs0[16 + l];
  f4 x10 = v10 + hs1[l];
  f4 x11 = v11 + hs1[16 + l];

  float ss0 = (x00.x + x00.y + x00.z + x00.w) + (x01.x + x01.y + x01.z + x01.w);
  float qq0 = (x00.x*x00.x + x00.y*x00.y + x00.z*x00.z + x00.w*x00.w)
            + (x01.x*x01.x + x01.y*x01.y + x01.z*x01.z + x01.w*x01.w);
  float ss1 = (x10.x + x10.y + x10.z + x10.w) + (x11.x + x11.y + x11.z + x11.w);
  float qq1 = (x10.x*x10.x + x10.y*x10.y + x10.z*x10.z + x10.w*x10.w)
            + (x11.x*x11.x + x11.y*x11.y + x11.z*x11.z + x11.w*x11.w);
#pragma unroll
  for (int m = 1; m < 16; m <<= 1) {
    ss0 += __shfl_xor(ss0, m);
    qq0 += __shfl_xor(qq0, m);
    ss1 += __shfl_xor(ss1, m);
    qq1 += __shfl_xor(qq1, m);
  }
  float mean0 = ss0 * (1.f / 128.f);
  float inv0 = rsqrtf(qq0 * (1.f / 128.f) - mean0 * mean0 + 1e-5f);
  float mean1 = ss1 * (1.f / 128.f);
  float inv1 = rsqrtf(qq1 * (1.f / 128.f) - mean1 * mean1 + 1e-5f);

  const f4* LW4 = (const f4*)ln_w;
  const f4* LB4 = (const f4*)ln_b;
  f4 w0 = LW4[l], w1 = LW4[16 + l];
  f4 bb0 = LB4[l], bb1 = LB4[16 + l];

  f4 o;
  f4* HO4 = (f4*)Hout;
  o.x = (x00.x - mean0) * inv0 * w0.x + bb0.x;
  o.y = (x00.y - mean0) * inv0 * w0.y + bb0.y;
  o.z = (x00.z - mean0) * inv0 * w0.z + bb0.z;
  o.w = (x00.w - mean0) * inv0 * w0.w + bb0.w;
  ntstore4(&HO4[r0 + l], o);
  o.x = (x01.x - mean0) * inv0 * w1.x + bb1.x;
  o.y = (x01.y - mean0) * inv0 * w1.y + bb1.y;
  o.z = (x01.z - mean0) * inv0 * w1.z + bb1.z;
  o.w = (x01.w - mean0) * inv0 * w1.w + bb1.w;
  ntstore4(&HO4[r0 + 16 + l], o);
  o.x = (x10.x - mean1) * inv1 * w0.x + bb0.x;
  o.y = (x10.y - mean1) * inv1 * w0.y + bb0.y;
  o.z = (x10.z - mean1) * inv1 * w0.z + bb0.z;
  o.w = (x10.w - mean1) * inv1 * w0.w + bb0.w;
  ntstore4(&HO4[r1 + l], o);
  o.x = (x11.x - mean1) * inv1 * w1.x + bb1.x;
  o.y = (x11.y - mean1) * inv1 * w1.y + bb1.y;
  o.z = (x11.z - mean1) * inv1 * w1.z + bb1.z;
  o.w = (x11.w - mean1) * inv1 * w1.w + bb1.w;
  ntstore4(&HO4[r1 + 16 + l], o);

  // --- Z path: threads 0..95, one f4 row each ---
  if (t < 96) {
    int sz = min(zuid - uid_lo, 1);
    float zz[4] = {zv.x, zv.y, zv.z, zv.w};
    float oo[4];
#pragma unroll
    for (int k = 0; k < 4; ++k) {
      int j = zcomp * 4 + k;
      int c = j / 3;
      float zcv = zc_s[sz][j];
      float r = resc_s[sz][c];
      oo[k] = zcv + (zz[k] - zcv) * r;
    }
    f4 ov = {oo[0], oo[1], oo[2], oo[3]};
    ntstore4(&((f4*)Zout)[(base + za) * 3 + zcomp], ov);
  }
}

extern "C" void kernel_launch(void* const* d_in, const int* in_sizes, int n_in,
                              void* d_out, int out_size, void* d_ws, size_t ws_size,
                              hipStream_t stream) {
  const float* H     = (const float*)d_in[0];
  const float* Z     = (const float*)d_in[1];
  const float* sigma = (const float*)d_in[2];
  const float* W1    = (const float*)d_in[3];
  const float* b1    = (const float*)d_in[4];
  const float* W2    = (const float*)d_in[5];
  const float* b2    = (const float*)d_in[6];
  const float* ln_w  = (const float*)d_in[7];
  const float* ln_b  = (const float*)d_in[8];
  const int* block_id = (const int*)d_in[9];
  const int* batch_id = (const int*)d_in[10];

  float* ws   = (float*)d_ws;
  float* acc  = ws + ACC_OFF;
  unsigned char* uid8 = (unsigned char*)(ws + UID_OFF);

  float* Hout = (float*)d_out;
  float* Zout = Hout + (size_t)N_ATOMS * DH;
  float* resc_out = Zout + (size_t)N_ATOMS * 12;

  hipMemsetAsync(acc, 0, BATCHES * 17 * sizeof(float), stream);
  k1_stats<<<(N_ATOMS + 255) / 256, 256, 0, stream>>>(Z, block_id, batch_id, acc, uid8);
  k3_apply<<<N_ATOMS / 32, 256, 0, stream>>>(H, Z, uid8, sigma, W1, b1, W2, b2,
                                             ln_w, ln_b, acc, Hout, Zout, resc_out);
}

// Round 5
// 103.211 us; speedup vs baseline: 1.5329x; 1.5329x over previous
//
#include <hip/hip_runtime.h>
#include <hip/hip_bf16.h>

#define N_ATOMS 400000
#define BATCHES 64
#define DH 128

// Workspace float layout
#define ACC_OFF 0          // B*17 : [cnt, zsum[12], zsq[4]] per batch
#define ZC_OFF  1088       // B*12
#define RS_OFF  1856       // B*4
#define HB_OFF  2112       // B*128
#define UID_OFF 10304      // N_ATOMS bytes (as uint8), starts at float offset 10304

typedef float f4 __attribute__((ext_vector_type(4)));

__device__ __forceinline__ f4 ntload4(const f4* p) { return __builtin_nontemporal_load(p); }
__device__ __forceinline__ float silu_f(float x) { return x / (1.f + expf(-x)); }

// ---------------- Kernel 1: per-batch stats (cnt, Zsum, Zsqsum) + uid8 ----------------
__global__ __launch_bounds__(256) void k1_stats(
    const float* __restrict__ Z, const int* __restrict__ block_id,
    const int* __restrict__ batch_id, float* __restrict__ acc,
    unsigned char* __restrict__ uid8) {
  __shared__ float bins[BATCHES * 17];
  for (int i = threadIdx.x; i < BATCHES * 17; i += 256) bins[i] = 0.f;
  __syncthreads();

  const f4* Z4 = (const f4*)Z;
  int n = blockIdx.x * 256 + threadIdx.x;
  bool valid = (n < N_ATOMS);
  int uid = -1;
  float z[12];
#pragma unroll
  for (int j = 0; j < 12; ++j) z[j] = 0.f;
  if (valid) {
    uid = batch_id[block_id[n]];
    uid8[n] = (unsigned char)uid;
    f4 a = Z4[n * 3 + 0];
    f4 b = Z4[n * 3 + 1];
    f4 c = Z4[n * 3 + 2];
    z[0] = a.x; z[1] = a.y; z[2]  = a.z; z[3]  = a.w;
    z[4] = b.x; z[5] = b.y; z[6]  = b.z; z[7]  = b.w;
    z[8] = c.x; z[9] = c.y; z[10] = c.z; z[11] = c.w;
  }

  int lo = valid ? uid : 0x7fffffff;
  int hi = uid;
#pragma unroll
  for (int m = 32; m; m >>= 1) {
    lo = min(lo, __shfl_xor(lo, m));
    hi = max(hi, __shfl_xor(hi, m));
  }

  if (lo == hi) {
    // wave-uniform uid (common case: sorted input)
    float vals[16];
#pragma unroll
    for (int j = 0; j < 12; ++j) vals[j] = z[j];
#pragma unroll
    for (int c = 0; c < 4; ++c)
      vals[12 + c] = z[c*3]*z[c*3] + z[c*3+1]*z[c*3+1] + z[c*3+2]*z[c*3+2];
#pragma unroll
    for (int v = 0; v < 16; ++v) {
      float x = vals[v];
#pragma unroll
      for (int m = 32; m; m >>= 1) x += __shfl_xor(x, m);
      vals[v] = x;
    }
    unsigned long long mb = __ballot(valid);
    if ((threadIdx.x & 63) == 0) {
      atomicAdd(&bins[hi * 17 + 0], (float)__popcll(mb));
#pragma unroll
      for (int v = 0; v < 16; ++v) atomicAdd(&bins[hi * 17 + 1 + v], vals[v]);
    }
  } else if (hi >= 0) {
    // rare: wave straddles a batch boundary -> per-lane LDS atomics
    if (valid) {
      atomicAdd(&bins[uid * 17 + 0], 1.f);
#pragma unroll
      for (int j = 0; j < 12; ++j) atomicAdd(&bins[uid * 17 + 1 + j], z[j]);
#pragma unroll
      for (int c = 0; c < 4; ++c)
        atomicAdd(&bins[uid * 17 + 13 + c],
                  z[c*3]*z[c*3] + z[c*3+1]*z[c*3+1] + z[c*3+2]*z[c*3+2]);
    }
  }
  __syncthreads();
  for (int i = threadIdx.x; i < BATCHES * 17; i += 256) {
    float v = bins[i];
    if (v != 0.f) atomicAdd(&acc[i], v);
  }
}

// ---------------- Kernel 2: rescale + RBF + 2-layer MLP (per batch row) ----------------
__global__ __launch_bounds__(128) void k2_mlp(
    const float* __restrict__ sigma, const float* __restrict__ W1,
    const float* __restrict__ b1, const float* __restrict__ W2,
    const float* __restrict__ b2, const float* __restrict__ acc,
    float* __restrict__ Zc, float* __restrict__ resc,
    float* __restrict__ hbuf, float* __restrict__ resc_out) {
  int b = blockIdx.x, t = threadIdx.x;
  __shared__ float rbf_s[64];
  __shared__ float h1_s[128];
  __shared__ float resc_s[4];

  if (t < 4) {
    int c = t;
    float cnt = acc[b * 17];
    float cs = fmaxf(cnt, 1.f);
    float s2 = 0.f;
#pragma unroll
    for (int a = 0; a < 3; ++a) {
      float zc = acc[b * 17 + 1 + c * 3 + a] / cs;
      Zc[b * 12 + c * 3 + a] = zc;
      s2 += zc * zc;
    }
    float sq = acc[b * 17 + 13 + c] - cnt * s2;
    float denom = fmaxf(cnt * 3.f - 1.f, 1.f);
    float var = fmaxf(sq / denom, 0.f);
    float r = sigma[c] / sqrtf(var);
    resc_s[c] = r;
    resc[b * 4 + c] = r;
    resc_out[b * 4 + c] = r;
  }
  __syncthreads();
  if (t < 64) {
    int c = t >> 4, ri = t & 15;
    float ds = resc_s[c] * (1.f / 7.f);
    float env = 0.f;
    if (ds < 1.f) {
      float d2 = ds * ds;
      float d5 = d2 * d2 * ds;
      env = 1.f - 21.f * d5 + 35.f * d5 * ds - 15.f * d5 * d2;
    }
    float off = (float)ri * (1.f / 15.f);
    float dd = ds - off;
    rbf_s[t] = env * expf(-112.5f * dd * dd);
  }
  __syncthreads();
  float s = b1[t];
#pragma unroll 8
  for (int k = 0; k < 64; ++k) s += rbf_s[k] * W1[k * 128 + t];
  h1_s[t] = silu_f(s);
  __syncthreads();
  float s2 = b2[t];
#pragma unroll 8
  for (int k = 0; k < 128; ++k) s2 += h1_s[k] * W2[k * 128 + t];
  hbuf[b * 128 + t] = silu_f(s2);
}

// ---------------- Kernel 3: per-atom apply (Z out + H add + LayerNorm) ----------------
// 256 threads = 16 subgroups of 16 lanes; each subgroup handles 4 atoms
// (lane owns two f4 quarters of each 128-float row). 64 atoms per block.
__global__ __launch_bounds__(256) void k3_apply(
    const float* __restrict__ H, const float* __restrict__ Z,
    const unsigned char* __restrict__ uid8,
    const float* __restrict__ ln_w, const float* __restrict__ ln_b,
    const float* __restrict__ Zc, const float* __restrict__ resc,
    const float* __restrict__ hbuf,
    float* __restrict__ Hout, float* __restrict__ Zout) {
  int t = threadIdx.x;
  int sub = t >> 4, l = t & 15;
  int base = blockIdx.x * 64;
  int n0 = base + sub * 4;

  unsigned int u4 = *(const unsigned int*)&uid8[n0];
  int uid[4] = {(int)(u4 & 0xff), (int)((u4 >> 8) & 0xff),
                (int)((u4 >> 16) & 0xff), (int)(u4 >> 24)};

  const f4* H4 = (const f4*)H;
  const f4* HB4 = (const f4*)hbuf;

  f4 va[4], vb[4];
#pragma unroll
  for (int a = 0; a < 4; ++a) {
    size_t r = (size_t)(n0 + a) * 32;
    va[a] = ntload4(&H4[r + l]);
    vb[a] = ntload4(&H4[r + 16 + l]);
  }
  f4 xa[4], xb[4];
#pragma unroll
  for (int a = 0; a < 4; ++a) {
    xa[a] = va[a] + HB4[uid[a] * 32 + l];
    xb[a] = vb[a] + HB4[uid[a] * 32 + 16 + l];
  }

  float s[4], q[4];
#pragma unroll
  for (int a = 0; a < 4; ++a) {
    s[a] = (xa[a].x + xa[a].y + xa[a].z + xa[a].w)
         + (xb[a].x + xb[a].y + xb[a].z + xb[a].w);
    q[a] = (xa[a].x*xa[a].x + xa[a].y*xa[a].y + xa[a].z*xa[a].z + xa[a].w*xa[a].w)
         + (xb[a].x*xb[a].x + xb[a].y*xb[a].y + xb[a].z*xb[a].z + xb[a].w*xb[a].w);
  }
#pragma unroll
  for (int m = 1; m < 16; m <<= 1) {
#pragma unroll
    for (int a = 0; a < 4; ++a) {
      s[a] += __shfl_xor(s[a], m);
      q[a] += __shfl_xor(q[a], m);
    }
  }

  const f4* LW4 = (const f4*)ln_w;
  const f4* LB4 = (const f4*)ln_b;
  f4 w0 = LW4[l], w1 = LW4[16 + l];
  f4 bb0 = LB4[l], bb1 = LB4[16 + l];

  f4* HO4 = (f4*)Hout;
#pragma unroll
  for (int a = 0; a < 4; ++a) {
    float mean = s[a] * (1.f / 128.f);
    float inv = rsqrtf(q[a] * (1.f / 128.f) - mean * mean + 1e-5f);
    size_t r = (size_t)(n0 + a) * 32;
    f4 o;
    o.x = (xa[a].x - mean) * inv * w0.x + bb0.x;
    o.y = (xa[a].y - mean) * inv * w0.y + bb0.y;
    o.z = (xa[a].z - mean) * inv * w0.z + bb0.z;
    o.w = (xa[a].w - mean) * inv * w0.w + bb0.w;
    HO4[r + l] = o;
    o.x = (xb[a].x - mean) * inv * w1.x + bb1.x;
    o.y = (xb[a].y - mean) * inv * w1.y + bb1.y;
    o.z = (xb[a].z - mean) * inv * w1.z + bb1.z;
    o.w = (xb[a].w - mean) * inv * w1.w + bb1.w;
    HO4[r + 16 + l] = o;
  }

  // Z path: threads 0..191 each handle one f4 row (atom = base + t/3, comp = t%3)
  if (t < 192) {
    int atom = base + t / 3;
    int comp = t - (t / 3) * 3;
    int zuid = uid8[atom];
    const f4* Z4 = (const f4*)Z;
    f4 z = Z4[atom * 3 + comp];
    float zz[4] = {z.x, z.y, z.z, z.w};
    float oo[4];
#pragma unroll
    for (int k = 0; k < 4; ++k) {
      int j = comp * 4 + k;
      int c = j / 3;
      float zcv = Zc[zuid * 12 + j];
      float r = resc[zuid * 4 + c];
      oo[k] = zcv + (zz[k] - zcv) * r;
    }
    f4 ov = {oo[0], oo[1], oo[2], oo[3]};
    ((f4*)Zout)[atom * 3 + comp] = ov;
  }
}

extern "C" void kernel_launch(void* const* d_in, const int* in_sizes, int n_in,
                              void* d_out, int out_size, void* d_ws, size_t ws_size,
                              hipStream_t stream) {
  const float* H     = (const float*)d_in[0];
  const float* Z     = (const float*)d_in[1];
  const float* sigma = (const float*)d_in[2];
  const float* W1    = (const float*)d_in[3];
  const float* b1    = (const float*)d_in[4];
  const float* W2    = (const float*)d_in[5];
  const float* b2    = (const float*)d_in[6];
  const float* ln_w  = (const float*)d_in[7];
  const float* ln_b  = (const float*)d_in[8];
  const int* block_id = (const int*)d_in[9];
  const int* batch_id = (const int*)d_in[10];

  float* ws   = (float*)d_ws;
  float* acc  = ws + ACC_OFF;
  float* Zc   = ws + ZC_OFF;
  float* resc = ws + RS_OFF;
  float* hbuf = ws + HB_OFF;
  unsigned char* uid8 = (unsigned char*)(ws + UID_OFF);

  float* Hout = (float*)d_out;
  float* Zout = Hout + (size_t)N_ATOMS * DH;
  float* resc_out = Zout + (size_t)N_ATOMS * 12;

  hipMemsetAsync(acc, 0, BATCHES * 17 * sizeof(float), stream);
  k1_stats<<<(N_ATOMS + 255) / 256, 256, 0, stream>>>(Z, block_id, batch_id, acc, uid8);
  k2_mlp<<<BATCHES, 128, 0, stream>>>(sigma, W1, b1, W2, b2, acc, Zc, resc, hbuf, resc_out);
  k3_apply<<<N_ATOMS / 64, 256, 0, stream>>>(H, Z, uid8, ln_w, ln_b,
                                             Zc, resc, hbuf, Hout, Zout);
}